// Round 3
// baseline (992.104 us; speedup 1.0000x reference)
//
#include <hip/hip_runtime.h>
#include <hip/hip_bf16.h>
#include <math.h>

// Problem constants
#define NN 10000      // nodes
#define NE 160000     // edges
#define ND 288        // edge feature dim
#define NCH 4         // node chunks for M
#define NPC (NN/NCH)  // 2500 nodes per chunk
#define EC 64         // edges per LDS round in k_node
#define H2P 68        // h2sT row stride (pad, mult of 4 for float4 alignment)

// ws layout (floats then ints), ~65.3 MB total (known-safe <= 87 MB):
//  T   [64*64*32] : 5 * sum_d Wq2[i,c*32+d]*Wk2[j,c*32+d]
//  U   [64*32]    : 5 * sum_d bq2[c*32+d]*Wk2[j,c*32+d]
//  Hq  [NN*64]    : per-node Q-MLP hidden
//  h2g [NE*64]    : K-MLP hidden, SORTED edge order
//  Mch [NPC*2048] : per-chunk M[n][j][c] (reused across 4 chunks)
//  cnt[NN], cur[NN], offs[NN+1], sorted[NE]

__device__ __forceinline__ float silu_f(float x){ return x / (1.0f + __expf(-x)); }

__global__ void k_hist(const int* __restrict__ ec, int* __restrict__ cnt){
    int e = blockIdx.x*256 + threadIdx.x;
    if (e < NE) atomicAdd(&cnt[ec[e]], 1);
}

__global__ void k_scan(const int* __restrict__ cnt, int* __restrict__ offs){
    __shared__ int part[1024];
    int tid = threadIdx.x;
    int base = tid*10;
    int s = 0;
    #pragma unroll
    for (int i=0;i<10;i++){ int idx=base+i; s += (idx<NN)? cnt[idx] : 0; }
    part[tid] = s;
    __syncthreads();
    for (int off=1; off<1024; off<<=1){
        int v = (tid>=off)? part[tid-off] : 0;
        __syncthreads();
        part[tid] += v;
        __syncthreads();
    }
    int run = part[tid] - s;
    for (int i=0;i<10;i++){ int idx=base+i; if(idx<NN){ offs[idx]=run; run += cnt[idx]; } }
    if (tid==1023) offs[NN] = part[1023];
}

__global__ void k_scatter(const int* __restrict__ ec, const int* __restrict__ offs,
                          int* __restrict__ cur, int* __restrict__ sorted){
    int e = blockIdx.x*256 + threadIdx.x;
    if (e < NE){
        int n = ec[e];
        int p = offs[n] + atomicAdd(&cur[n], 1);
        sorted[p] = e;
    }
}

__global__ void k_T(const float* __restrict__ Wq2, const float* __restrict__ Wk2,
                    float* __restrict__ T){
    int idx = blockIdx.x*256 + threadIdx.x;   // i*2048 + j*32 + c
    int c = idx & 31, j = (idx>>5) & 63, i = idx >> 11;
    const float* a = Wq2 + i*1024 + c*32;
    const float* b = Wk2 + j*1024 + c*32;
    float s = 0.f;
    #pragma unroll
    for (int d=0; d<32; d++) s += a[d]*b[d];
    T[idx] = 5.0f*s;
}

__global__ void k_U(const float* __restrict__ bq2, const float* __restrict__ Wk2,
                    float* __restrict__ U){
    int idx = blockIdx.x*256 + threadIdx.x;   // 2048
    int j = idx>>5, c = idx&31; float s=0.f;
    #pragma unroll
    for (int d=0; d<32; d++) s += bq2[c*32+d]*Wk2[j*1024 + c*32 + d];
    U[idx] = 5.0f*s;
}

// per-node Q-MLP hidden: Hq[n] = silu(silu(attrs@Wq0+bq0)@Wq1+bq1), 4 nodes/block
__global__ __launch_bounds__(256) void k_H(const float* __restrict__ na,
                    const float* __restrict__ Wq0, const float* __restrict__ bq0,
                    const float* __restrict__ Wq1, const float* __restrict__ bq1,
                    float* __restrict__ Hq){
    __shared__ float W0s[4096], W1s[4096];
    __shared__ float as[4][64], h1s[4][64];
    int tid = threadIdx.x;
    for (int i=tid; i<4096; i+=256){ W0s[i]=Wq0[i]; W1s[i]=Wq1[i]; }
    int sg = tid>>6, lane = tid&63;
    int n = blockIdx.x*4 + sg;
    if (n < NN) as[sg][lane] = na[(size_t)n*64 + lane];
    __syncthreads();
    if (n < NN){
        float s = bq0[lane];
        #pragma unroll
        for (int i=0;i<64;i++) s += as[sg][i]*W0s[i*64+lane];
        h1s[sg][lane] = silu_f(s);
    }
    __syncthreads();
    if (n < NN){
        float s = bq1[lane];
        #pragma unroll
        for (int i=0;i<64;i++) s += h1s[sg][i]*W1s[i*64+lane];
        Hq[(size_t)n*64 + lane] = silu_f(s);
    }
}

// K-MLP for 64 sorted edges/block; h2 written in sorted order.
// Weights read via wave-uniform scalar path (readfirstlane base -> s_load).
__global__ __launch_bounds__(256) void k_kmlp(
        const float* __restrict__ ef, const int* __restrict__ sorted,
        const float* __restrict__ Wk0, const float* __restrict__ bk0,
        const float* __restrict__ Wk1, const float* __restrict__ bk1,
        float* __restrict__ h2g){
    __shared__ float xs[64*33];
    __shared__ float h1s[64*65];
    __shared__ float h2s[64*66];
    __shared__ int   es[64];
    int tid = threadIdx.x;
    int p0 = blockIdx.x*64;
    if (tid < 64) es[tid] = sorted[p0+tid];
    __syncthreads();
    for (int idx=tid; idx<2048; idx+=256){
        int k = idx>>5, i = idx&31;
        xs[k*33+i] = ef[(size_t)es[k]*ND + i];
    }
    __syncthreads();
    int e = tid & 63;
    int o0 = __builtin_amdgcn_readfirstlane((tid>>6)*16);
    {   // h1
        float acc[16];
        #pragma unroll
        for (int t=0;t<16;t++) acc[t] = bk0[o0+t];
        for (int i=0;i<32;i++){
            float xv = xs[e*33+i];
            const float* wr = Wk0 + i*64 + o0;
            #pragma unroll
            for (int t=0;t<16;t++) acc[t] = fmaf(xv, wr[t], acc[t]);
        }
        #pragma unroll
        for (int t=0;t<16;t++) h1s[e*65+o0+t] = silu_f(acc[t]);
    }
    __syncthreads();
    {   // h2
        float acc[16];
        #pragma unroll
        for (int t=0;t<16;t++) acc[t] = bk1[o0+t];
        for (int j=0;j<64;j++){
            float hv = h1s[e*65+j];
            const float* wr = Wk1 + j*64 + o0;
            #pragma unroll
            for (int t=0;t<16;t++) acc[t] = fmaf(hv, wr[t], acc[t]);
        }
        #pragma unroll
        for (int t=0;t<16;t++) h2s[e*66+o0+t] = silu_f(acc[t]);
    }
    __syncthreads();
    for (int idx=tid; idx<4096; idx+=256)
        h2g[(size_t)p0*64 + idx] = h2s[(idx>>6)*66 + (idx&63)];
}

// M[n][j][c] = sum_i Hq[n,i]*T[i,j,c] + U[j,c], for one 32-node tile.
// Hq via scalar loads (block-uniform index), T via coalesced float4.
__global__ __launch_bounds__(256) void k_M(
        const float* __restrict__ Hq, const float* __restrict__ T,
        const float* __restrict__ U, float* __restrict__ M, int nbase){
    int tid = threadIdx.x;
    int nb = blockIdx.x*32;              // local node base within chunk
    int n0 = __builtin_amdgcn_readfirstlane((tid>>6)*8);
    int lane = tid & 63;
    for (int r=0;r<8;r++){
        int jc0 = lane*4 + r*256;
        float acc[8][4];
        float4 uv = *(const float4*)&U[jc0];
        #pragma unroll
        for (int t=0;t<8;t++){ acc[t][0]=uv.x; acc[t][1]=uv.y; acc[t][2]=uv.z; acc[t][3]=uv.w; }
        for (int i=0;i<64;i++){
            float4 tv = *(const float4*)&T[i*2048 + jc0];
            #pragma unroll
            for (int t=0;t<8;t++){
                int nn = nbase + nb + n0 + t;
                float hv = Hq[(size_t)(nn < NN ? nn : NN-1)*64 + i];
                acc[t][0] = fmaf(hv, tv.x, acc[t][0]);
                acc[t][1] = fmaf(hv, tv.y, acc[t][1]);
                acc[t][2] = fmaf(hv, tv.z, acc[t][2]);
                acc[t][3] = fmaf(hv, tv.w, acc[t][3]);
            }
        }
        #pragma unroll
        for (int t=0;t<8;t++){
            int nl = nb + n0 + t;
            if (nl < NPC && nbase + nl < NN){
                float4 o; o.x=acc[t][0]; o.y=acc[t][1]; o.z=acc[t][2]; o.w=acc[t][3];
                *(float4*)&M[(size_t)nl*2048 + jc0] = o;
            }
        }
    }
}

// One block per node: logits from h2 (sorted, contiguous) x M[n], online
// segment softmax, irreps-weighted accumulation. 256 threads, 64-edge rounds.
__global__ __launch_bounds__(256) void k_node(
        const float* __restrict__ ef, const float* __restrict__ h2g,
        const float* __restrict__ Mc,
        const int* __restrict__ offs, const int* __restrict__ sorted,
        float* __restrict__ out, int nbase){
    __shared__ float h2sT[64*H2P];   // [j][k] transposed
    __shared__ float Ms[2048];       // [j][c]
    __shared__ float Ls[64*32];      // logits, then p in place
    __shared__ float msh[32], zsh[32], rsh[32];
    __shared__ int   es[64];

    int tid = threadIdx.x;
    int n = nbase + blockIdx.x;
    int o0 = offs[n], o1 = offs[n+1];
    int count = o1 - o0;
    const float* Mn = Mc + (size_t)blockIdx.x*2048;
    {
        const float4* m4 = (const float4*)Mn;
        float4* s4 = (float4*)Ms;
        for (int idx=tid; idx<512; idx+=256) s4[idx] = m4[idx];
    }
    if (tid < 32){ msh[tid] = -INFINITY; zsh[tid] = 0.f; rsh[tid] = 0.f; }

    int col = tid;
    int chcol  = (col<32)? col : (col<128)? (col-32)/3 : (col-128)/5;
    int col1   = 256 + tid;          // only tid<32
    int chcol1 = (128 + tid)/5;      // (col1-128)/5
    float acc0 = 0.f, acc1 = 0.f;
    __syncthreads();

    for (int base=0; base<count; base+=EC){
        int ne = min(EC, count-base);
        if (tid < 64) es[tid] = (tid < ne) ? sorted[o0+base+tid] : 0;
        for (int idx=tid; idx<4096; idx+=256){
            int k = idx>>6, j = idx&63;
            h2sT[j*H2P + k] = (k < ne) ? h2g[(size_t)(o0+base+k)*64 + j] : 0.f;
        }
        __syncthreads();
        if (tid < 64){   // logits: 8k x 4c register tile per thread
            int k0 = (tid&7)*8, c0 = (tid>>3)*4;
            float acc[8][4];
            #pragma unroll
            for (int kk=0;kk<8;kk++){
                #pragma unroll
                for (int cc=0;cc<4;cc++) acc[kk][cc] = 0.f;
            }
            for (int j=0;j<64;j++){
                float4 va0 = *(const float4*)&h2sT[j*H2P + k0];
                float4 va1 = *(const float4*)&h2sT[j*H2P + k0 + 4];
                float4 vm  = *(const float4*)&Ms[j*32 + c0];
                float va[8] = {va0.x,va0.y,va0.z,va0.w, va1.x,va1.y,va1.z,va1.w};
                #pragma unroll
                for (int kk=0;kk<8;kk++){
                    acc[kk][0] = fmaf(va[kk], vm.x, acc[kk][0]);
                    acc[kk][1] = fmaf(va[kk], vm.y, acc[kk][1]);
                    acc[kk][2] = fmaf(va[kk], vm.z, acc[kk][2]);
                    acc[kk][3] = fmaf(va[kk], vm.w, acc[kk][3]);
                }
            }
            #pragma unroll
            for (int kk=0;kk<8;kk++){
                float4 o; o.x=acc[kk][0]; o.y=acc[kk][1]; o.z=acc[kk][2]; o.w=acc[kk][3];
                *(float4*)&Ls[(k0+kk)*32 + c0] = o;
            }
        }
        __syncthreads();
        if (tid < 32){   // online softmax update, p stored in place
            int c = tid;
            float mold = msh[c], lmax = mold;
            for (int k=0;k<ne;k++) lmax = fmaxf(lmax, Ls[k*32+c]);
            float rr = __expf(mold - lmax);     // 0 on first round
            float zz = zsh[c]*rr;
            for (int k=0;k<ne;k++){
                float pp = __expf(Ls[k*32+c] - lmax);
                Ls[k*32+c] = pp; zz += pp;
            }
            zsh[c]=zz; msh[c]=lmax; rsh[c]=rr;
        }
        __syncthreads();
        {   // accumulate
            acc0 *= rsh[chcol];
            if (tid < 32) acc1 *= rsh[chcol1];
            for (int k=0;k<ne;k++){
                const float* efr = ef + (size_t)es[k]*ND;
                acc0 = fmaf(Ls[k*32+chcol], efr[col], acc0);
                if (tid < 32) acc1 = fmaf(Ls[k*32+chcol1], efr[col1], acc1);
            }
        }
        __syncthreads();
    }
    out[(size_t)n*ND + col] = (count>0) ? acc0/zsh[chcol] : 0.f;
    if (tid < 32)
        out[(size_t)n*ND + col1] = (count>0) ? acc1/zsh[chcol1] : 0.f;
}

extern "C" void kernel_launch(void* const* d_in, const int* in_sizes, int n_in,
                              void* d_out, int out_size, void* d_ws, size_t ws_size,
                              hipStream_t stream) {
    const float* edge_feat  = (const float*)d_in[0];
    const float* node_attrs = (const float*)d_in[1];
    const int*   edge_center= (const int*)  d_in[2];
    const float* Wq0 = (const float*)d_in[3];  const float* bq0 = (const float*)d_in[4];
    const float* Wq1 = (const float*)d_in[5];  const float* bq1 = (const float*)d_in[6];
    const float* Wq2 = (const float*)d_in[7];  const float* bq2 = (const float*)d_in[8];
    const float* Wk0 = (const float*)d_in[9];  const float* bk0 = (const float*)d_in[10];
    const float* Wk1 = (const float*)d_in[11]; const float* bk1 = (const float*)d_in[12];
    const float* Wk2 = (const float*)d_in[13]; const float* bk2 = (const float*)d_in[14];
    float* out = (float*)d_out;

    float* T    = (float*)d_ws;                  // 131072
    float* U    = T + 131072;                    // 2048
    float* Hq   = U + 2048;                      // 640000
    float* h2g  = Hq + (size_t)NN*64;            // 10,240,000
    float* Mch  = h2g + (size_t)NE*64;           // 5,120,000
    int*   cnt  = (int*)(Mch + (size_t)NPC*2048);
    int*   cur  = cnt + NN;
    int*   offs = cur + NN;
    int*   sorted = offs + NN + 1;

    hipMemsetAsync(cnt, 0, 2*NN*sizeof(int), stream);

    k_hist   <<<(NE+255)/256, 256, 0, stream>>>(edge_center, cnt);
    k_scan   <<<1, 1024, 0, stream>>>(cnt, offs);
    k_scatter<<<(NE+255)/256, 256, 0, stream>>>(edge_center, offs, cur, sorted);
    k_T      <<<512, 256, 0, stream>>>(Wq2, Wk2, T);
    k_U      <<<8, 256, 0, stream>>>(bq2, Wk2, U);
    k_H      <<<(NN+3)/4, 256, 0, stream>>>(node_attrs, Wq0, bq0, Wq1, bq1, Hq);
    k_kmlp   <<<NE/64, 256, 0, stream>>>(edge_feat, sorted, Wk0, bk0, Wk1, bk1, h2g);

    for (int c=0; c<NCH; c++){
        int nbase = c*NPC;
        k_M   <<<(NPC+31)/32, 256, 0, stream>>>(Hq, T, U, Mch, nbase);
        k_node<<<NPC, 256, 0, stream>>>(edge_feat, h2g, Mch, offs, sorted, out, nbase);
    }
}

// Round 4
// 489.754 us; speedup vs baseline: 2.0257x; 2.0257x over previous
//
#include <hip/hip_runtime.h>
#include <hip/hip_bf16.h>
#include <math.h>

// Problem constants
#define NN 10000      // nodes
#define NE 160000     // edges
#define ND 288        // edge feature dim

// ws layout (floats then ints), ~147 MB (ws_size ~720 MB per fill counter):
//  T   [64*64*32] : 5 * sum_d Wq2[i,c*32+d]*Wk2[j,c*32+d]
//  U   [64*32]    : 5 * sum_d bq2[c*32+d]*Wk2[j,c*32+d]
//  Hq  [NN*64]    : per-node Q-MLP hidden
//  h2g [NE*64]    : K-MLP hidden, SORTED edge order
//  M   [NN*2048]  : M[n][j][c]
//  Lg  [NE*32]    : logits, SORTED edge order
//  cnt[NN], cur[NN], offs[NN+1], sorted[NE]

__device__ __forceinline__ float silu_f(float x){ return x / (1.0f + __expf(-x)); }

__global__ void k_hist(const int* __restrict__ ec, int* __restrict__ cnt){
    int e = blockIdx.x*256 + threadIdx.x;
    if (e < NE) atomicAdd(&cnt[ec[e]], 1);
}

__global__ void k_scan(const int* __restrict__ cnt, int* __restrict__ offs){
    __shared__ int part[1024];
    int tid = threadIdx.x;
    int base = tid*10;
    int s = 0;
    #pragma unroll
    for (int i=0;i<10;i++){ int idx=base+i; s += (idx<NN)? cnt[idx] : 0; }
    part[tid] = s;
    __syncthreads();
    for (int off=1; off<1024; off<<=1){
        int v = (tid>=off)? part[tid-off] : 0;
        __syncthreads();
        part[tid] += v;
        __syncthreads();
    }
    int run = part[tid] - s;
    for (int i=0;i<10;i++){ int idx=base+i; if(idx<NN){ offs[idx]=run; run += cnt[idx]; } }
    if (tid==1023) offs[NN] = part[1023];
}

__global__ void k_scatter(const int* __restrict__ ec, const int* __restrict__ offs,
                          int* __restrict__ cur, int* __restrict__ sorted){
    int e = blockIdx.x*256 + threadIdx.x;
    if (e < NE){
        int n = ec[e];
        int p = offs[n] + atomicAdd(&cur[n], 1);
        sorted[p] = e;
    }
}

__global__ void k_T(const float* __restrict__ Wq2, const float* __restrict__ Wk2,
                    float* __restrict__ T){
    int idx = blockIdx.x*256 + threadIdx.x;   // i*2048 + j*32 + c
    int c = idx & 31, j = (idx>>5) & 63, i = idx >> 11;
    const float* a = Wq2 + i*1024 + c*32;
    const float* b = Wk2 + j*1024 + c*32;
    float s = 0.f;
    #pragma unroll
    for (int d=0; d<32; d++) s += a[d]*b[d];
    T[idx] = 5.0f*s;
}

__global__ void k_U(const float* __restrict__ bq2, const float* __restrict__ Wk2,
                    float* __restrict__ U){
    int idx = blockIdx.x*256 + threadIdx.x;   // 2048
    int j = idx>>5, c = idx&31; float s=0.f;
    #pragma unroll
    for (int d=0; d<32; d++) s += bq2[c*32+d]*Wk2[j*1024 + c*32 + d];
    U[idx] = 5.0f*s;
}

// per-node Q-MLP hidden: Hq[n] = silu(silu(attrs@Wq0+bq0)@Wq1+bq1), 4 nodes/block
__global__ __launch_bounds__(256) void k_H(const float* __restrict__ na,
                    const float* __restrict__ Wq0, const float* __restrict__ bq0,
                    const float* __restrict__ Wq1, const float* __restrict__ bq1,
                    float* __restrict__ Hq){
    __shared__ float W0s[4096], W1s[4096];
    __shared__ float as[4][64], h1s[4][64];
    int tid = threadIdx.x;
    for (int i=tid; i<4096; i+=256){ W0s[i]=Wq0[i]; W1s[i]=Wq1[i]; }
    int sg = tid>>6, lane = tid&63;
    int n = blockIdx.x*4 + sg;
    if (n < NN) as[sg][lane] = na[(size_t)n*64 + lane];
    __syncthreads();
    if (n < NN){
        float s = bq0[lane];
        #pragma unroll
        for (int i=0;i<64;i++) s += as[sg][i]*W0s[i*64+lane];
        h1s[sg][lane] = silu_f(s);
    }
    __syncthreads();
    if (n < NN){
        float s = bq1[lane];
        #pragma unroll
        for (int i=0;i<64;i++) s += h1s[sg][i]*W1s[i*64+lane];
        Hq[(size_t)n*64 + lane] = silu_f(s);
    }
}

// K-MLP for 64 sorted edges/block; h2 written in sorted order.
__global__ __launch_bounds__(256) void k_kmlp(
        const float* __restrict__ ef, const int* __restrict__ sorted,
        const float* __restrict__ Wk0, const float* __restrict__ bk0,
        const float* __restrict__ Wk1, const float* __restrict__ bk1,
        float* __restrict__ h2g){
    __shared__ float xs[64*33];
    __shared__ float h1s[64*65];
    __shared__ float h2s[64*66];
    __shared__ int   es[64];
    int tid = threadIdx.x;
    int p0 = blockIdx.x*64;
    if (tid < 64) es[tid] = sorted[p0+tid];
    __syncthreads();
    for (int idx=tid; idx<2048; idx+=256){
        int k = idx>>5, i = idx&31;
        xs[k*33+i] = ef[(size_t)es[k]*ND + i];
    }
    __syncthreads();
    int e = tid & 63;
    int o0 = __builtin_amdgcn_readfirstlane((tid>>6)*16);
    {   // h1
        float acc[16];
        #pragma unroll
        for (int t=0;t<16;t++) acc[t] = bk0[o0+t];
        for (int i=0;i<32;i++){
            float xv = xs[e*33+i];
            const float* wr = Wk0 + i*64 + o0;
            #pragma unroll
            for (int t=0;t<16;t++) acc[t] = fmaf(xv, wr[t], acc[t]);
        }
        #pragma unroll
        for (int t=0;t<16;t++) h1s[e*65+o0+t] = silu_f(acc[t]);
    }
    __syncthreads();
    {   // h2
        float acc[16];
        #pragma unroll
        for (int t=0;t<16;t++) acc[t] = bk1[o0+t];
        for (int j=0;j<64;j++){
            float hv = h1s[e*65+j];
            const float* wr = Wk1 + j*64 + o0;
            #pragma unroll
            for (int t=0;t<16;t++) acc[t] = fmaf(hv, wr[t], acc[t]);
        }
        #pragma unroll
        for (int t=0;t<16;t++) h2s[e*66+o0+t] = silu_f(acc[t]);
    }
    __syncthreads();
    for (int idx=tid; idx<4096; idx+=256)
        h2g[(size_t)p0*64 + idx] = h2s[(idx>>6)*66 + (idx&63)];
}

// GEMM-shaped: M[n][jc] = sum_i Hq[n,i]*T[i,jc] + U[jc].
// Tile: 64 nodes x 256 jc per block; thread = 16n x 4jc; grid (157, 8).
__global__ __launch_bounds__(256) void k_M(
        const float* __restrict__ Hq, const float* __restrict__ T,
        const float* __restrict__ U, float* __restrict__ M){
    __shared__ float hs[64*65];
    int tid = threadIdx.x;
    int n0 = blockIdx.x*64;
    int jc = blockIdx.y*256 + (tid&63)*4;
    for (int idx=tid; idx<4096; idx+=256){
        int nn = idx>>6, i = idx&63;
        int n = n0+nn;
        hs[nn*65+i] = Hq[(size_t)(n<NN?n:NN-1)*64 + i];
    }
    __syncthreads();
    int tg = __builtin_amdgcn_readfirstlane(tid>>6)*16;   // wave-uniform node group
    float4 uv = *(const float4*)&U[jc];
    float acc[16][4];
    #pragma unroll
    for (int t=0;t<16;t++){ acc[t][0]=uv.x; acc[t][1]=uv.y; acc[t][2]=uv.z; acc[t][3]=uv.w; }
    for (int i=0;i<64;i++){
        float4 tv = *(const float4*)&T[i*2048 + jc];
        #pragma unroll
        for (int t=0;t<16;t++){
            float hv = hs[(tg+t)*65 + i];    // LDS broadcast within wave
            acc[t][0] = fmaf(hv, tv.x, acc[t][0]);
            acc[t][1] = fmaf(hv, tv.y, acc[t][1]);
            acc[t][2] = fmaf(hv, tv.z, acc[t][2]);
            acc[t][3] = fmaf(hv, tv.w, acc[t][3]);
        }
    }
    #pragma unroll
    for (int t=0;t<16;t++){
        int n = n0 + tg + t;
        if (n < NN){
            float4 o; o.x=acc[t][0]; o.y=acc[t][1]; o.z=acc[t][2]; o.w=acc[t][3];
            *(float4*)&M[(size_t)n*2048 + jc] = o;
        }
    }
}

// Edge-parallel logits: L[e,c] = sum_j h2[e,j] * M[n(e)][j*32+c].
// 64 sorted edges/block; M rows served by L2 (sort locality).
__global__ __launch_bounds__(256) void k_logit(
        const float* __restrict__ h2g, const float* __restrict__ Mg,
        const int* __restrict__ sorted, const int* __restrict__ ec,
        float* __restrict__ Lg){
    __shared__ float h2s[64*65];
    __shared__ int ns[64];
    int tid = threadIdx.x;
    int p0 = blockIdx.x*64;
    if (tid < 64) ns[tid] = ec[sorted[p0+tid]];
    for (int idx=tid; idx<4096; idx+=256)
        h2s[(idx>>6)*65 + (idx&63)] = h2g[(size_t)p0*64 + idx];
    __syncthreads();
    int e = tid>>2, cq = (tid&3)*8;
    const float* Mn = Mg + (size_t)ns[e]*2048 + cq;
    float acc[8];
    #pragma unroll
    for (int t=0;t<8;t++) acc[t]=0.f;
    for (int j=0;j<64;j++){
        float hv = h2s[e*65+j];
        float4 m0 = *(const float4*)&Mn[j*32];
        float4 m1 = *(const float4*)&Mn[j*32+4];
        acc[0] = fmaf(hv, m0.x, acc[0]);
        acc[1] = fmaf(hv, m0.y, acc[1]);
        acc[2] = fmaf(hv, m0.z, acc[2]);
        acc[3] = fmaf(hv, m0.w, acc[3]);
        acc[4] = fmaf(hv, m1.x, acc[4]);
        acc[5] = fmaf(hv, m1.y, acc[5]);
        acc[6] = fmaf(hv, m1.z, acc[6]);
        acc[7] = fmaf(hv, m1.w, acc[7]);
    }
    float* lp = Lg + (size_t)(p0+e)*32 + cq;
    float4 o0; o0.x=acc[0]; o0.y=acc[1]; o0.z=acc[2]; o0.w=acc[3];
    float4 o1; o1.x=acc[4]; o1.y=acc[5]; o1.z=acc[6]; o1.w=acc[7];
    *(float4*)lp = o0;
    *(float4*)(lp+4) = o1;
}

// One block per node: load precomputed logits (sorted, contiguous), online
// softmax, irreps-weighted ef accumulation. 320 threads (288 output cols).
__global__ __launch_bounds__(320) void k_node(
        const float* __restrict__ ef, const float* __restrict__ Lg,
        const int* __restrict__ offs, const int* __restrict__ sorted,
        float* __restrict__ out){
    __shared__ float Ls[64*32];     // logits, then p in place
    __shared__ float msh[32], zsh[32], rsh[32];
    __shared__ int   es[64];

    int tid = threadIdx.x;
    int n = blockIdx.x;
    int o0 = offs[n], count = offs[n+1] - o0;
    if (tid < 32){ msh[tid] = -INFINITY; zsh[tid] = 0.f; rsh[tid] = 0.f; }
    int col = tid;   // valid < 288
    int chcol = (col<32)? col : (col<128)? (col-32)/3 : (col-128)/5;
    float acc0 = 0.f;
    __syncthreads();

    for (int base=0; base<count; base+=64){
        int ne = min(64, count-base);
        if (tid < 64) es[tid] = (tid < ne) ? sorted[o0+base+tid] : 0;
        for (int idx=tid; idx<ne*32; idx+=320)
            Ls[idx] = Lg[(size_t)(o0+base)*32 + idx];
        __syncthreads();
        if (tid < 32){   // online softmax, p in place
            int c = tid;
            float mold = msh[c], lmax = mold;
            for (int k=0;k<ne;k++) lmax = fmaxf(lmax, Ls[k*32+c]);
            float rr = __expf(mold - lmax);     // 0 on first round
            float zz = zsh[c]*rr;
            for (int k=0;k<ne;k++){
                float pp = __expf(Ls[k*32+c] - lmax);
                Ls[k*32+c] = pp; zz += pp;
            }
            zsh[c]=zz; msh[c]=lmax; rsh[c]=rr;
        }
        __syncthreads();
        if (tid < 288){
            acc0 *= rsh[chcol];
            int k = 0;
            for (; k+4<=ne; k+=4){
                int e0=es[k], e1=es[k+1], e2=es[k+2], e3=es[k+3];
                float p0=Ls[k*32+chcol],     p1=Ls[(k+1)*32+chcol];
                float p2=Ls[(k+2)*32+chcol], p3=Ls[(k+3)*32+chcol];
                float v0=ef[(size_t)e0*ND+col], v1=ef[(size_t)e1*ND+col];
                float v2=ef[(size_t)e2*ND+col], v3=ef[(size_t)e3*ND+col];
                acc0 = fmaf(p0,v0,acc0); acc0 = fmaf(p1,v1,acc0);
                acc0 = fmaf(p2,v2,acc0); acc0 = fmaf(p3,v3,acc0);
            }
            for (; k<ne; k++)
                acc0 = fmaf(Ls[k*32+chcol], ef[(size_t)es[k]*ND+col], acc0);
        }
        __syncthreads();
    }
    if (tid < 288)
        out[(size_t)n*ND + col] = (count>0) ? acc0/zsh[chcol] : 0.f;
}

extern "C" void kernel_launch(void* const* d_in, const int* in_sizes, int n_in,
                              void* d_out, int out_size, void* d_ws, size_t ws_size,
                              hipStream_t stream) {
    const float* edge_feat  = (const float*)d_in[0];
    const float* node_attrs = (const float*)d_in[1];
    const int*   edge_center= (const int*)  d_in[2];
    const float* Wq0 = (const float*)d_in[3];  const float* bq0 = (const float*)d_in[4];
    const float* Wq1 = (const float*)d_in[5];  const float* bq1 = (const float*)d_in[6];
    const float* Wq2 = (const float*)d_in[7];  const float* bq2 = (const float*)d_in[8];
    const float* Wk0 = (const float*)d_in[9];  const float* bk0 = (const float*)d_in[10];
    const float* Wk1 = (const float*)d_in[11]; const float* bk1 = (const float*)d_in[12];
    const float* Wk2 = (const float*)d_in[13]; const float* bk2 = (const float*)d_in[14];
    float* out = (float*)d_out;

    float* T    = (float*)d_ws;                  // 131072
    float* U    = T + 131072;                    // 2048
    float* Hq   = U + 2048;                      // 640,000
    float* h2g  = Hq + (size_t)NN*64;            // 10,240,000
    float* M    = h2g + (size_t)NE*64;           // 20,480,000
    float* Lg   = M + (size_t)NN*2048;           // 5,120,000
    int*   cnt  = (int*)(Lg + (size_t)NE*32);
    int*   cur  = cnt + NN;
    int*   offs = cur + NN;
    int*   sorted = offs + NN + 1;

    hipMemsetAsync(cnt, 0, 2*NN*sizeof(int), stream);

    k_hist   <<<(NE+255)/256, 256, 0, stream>>>(edge_center, cnt);
    k_scan   <<<1, 1024, 0, stream>>>(cnt, offs);
    k_scatter<<<(NE+255)/256, 256, 0, stream>>>(edge_center, offs, cur, sorted);
    k_T      <<<512, 256, 0, stream>>>(Wq2, Wk2, T);
    k_U      <<<8, 256, 0, stream>>>(bq2, Wk2, U);
    k_H      <<<(NN+3)/4, 256, 0, stream>>>(node_attrs, Wq0, bq0, Wq1, bq1, Hq);
    k_kmlp   <<<NE/64, 256, 0, stream>>>(edge_feat, sorted, Wk0, bk0, Wk1, bk1, h2g);
    k_M      <<<dim3((NN+63)/64, 8), 256, 0, stream>>>(Hq, T, U, M);
    k_logit  <<<NE/64, 256, 0, stream>>>(h2g, M, sorted, edge_center, Lg);
    k_node   <<<NN, 320, 0, stream>>>(edge_feat, Lg, offs, sorted, out);
}